// Round 2
// 98.433 us; speedup vs baseline: 1.0904x; 1.0904x over previous
//
#include <hip/hip_runtime.h>
#include <stdint.h>

// Match XLA: no FMA contraction anywhere numerics feed comparisons.
#pragma clang fp contract(off)

#define B_IMG 32
#define R_N   6000
#define G_N   100
#define NS    128
#define PMAX  32
#define NBUCK 1024
#define BCAP  512
#define SEL_T 1024   // select_kernel block size
#define T_LOAD 750   // threads owning items in select (750*8 = 6000)
#define NITEM 8

#ifndef JAX_PARTITIONABLE
#define JAX_PARTITIONABLE 1
#endif

__device__ __forceinline__ uint32_t rotl32(uint32_t v, int d) {
  return (v << d) | (v >> (32 - d));
}

// Threefry-2x32, 20 rounds, exactly as jax/_src/prng.py
__device__ __forceinline__ void tf2x32(uint32_t k0, uint32_t k1,
                                       uint32_t x0, uint32_t x1,
                                       uint32_t& o0, uint32_t& o1) {
  const uint32_t k2 = k0 ^ k1 ^ 0x1BD11BDAu;
  x0 += k0; x1 += k1;
#define TF_R(r) { x0 += x1; x1 = rotl32(x1, r); x1 ^= x0; }
  TF_R(13) TF_R(15) TF_R(26) TF_R(6)
  x0 += k1; x1 += k2 + 1u;
  TF_R(17) TF_R(29) TF_R(16) TF_R(24)
  x0 += k2; x1 += k0 + 2u;
  TF_R(13) TF_R(15) TF_R(26) TF_R(6)
  x0 += k0; x1 += k1 + 3u;
  TF_R(17) TF_R(29) TF_R(16) TF_R(24)
  x0 += k1; x1 += k2 + 4u;
  TF_R(13) TF_R(15) TF_R(26) TF_R(6)
  x0 += k2; x1 += k0 + 5u;
#undef TF_R
  o0 = x0; o1 = x1;
}

// jax.random.uniform transform for float32, minval=1e-6, maxval=1.0
__device__ __forceinline__ float tf_uniform(uint32_t bits) {
#pragma clang fp contract(off)
  float f = __uint_as_float((bits >> 9) | 0x3f800000u) - 1.0f;
  float r = f * (1.0f - 1e-6f) + 1e-6f;   // mul then add, NOT fma
  return fmaxf(1e-6f, r);
}

// Kernel 1: per-roi r (threefry), IOU max + argmax vs 100 GTs.
// Writes: wr[o] = (maxIOU >= 0.5) ? -r : r   (class packed into sign bit)
//         wgta[o] = argmax gt index
__global__ __launch_bounds__(256) void prep_kernel(
    const float* __restrict__ roi, const float* __restrict__ gt,
    float* __restrict__ wr, int* __restrict__ wgta) {
#pragma clang fp contract(off)
  const int b = blockIdx.y;
  const int i = blockIdx.x * 256 + threadIdx.x;

  __shared__ __align__(16) float sg[G_N * 4];
  __shared__ float sga[G_N];
#if JAX_PARTITIONABLE
  __shared__ uint32_t skb[2];
#endif
  for (int t = threadIdx.x; t < G_N * 4; t += 256) sg[t] = gt[(size_t)b * G_N * 4 + t];
#if JAX_PARTITIONABLE
  if (threadIdx.x == 0) {
    uint32_t a, c;
    tf2x32(0u, 42u, 0u, (uint32_t)b, a, c);   // foldlike split: key_b (block-uniform)
    skb[0] = a; skb[1] = c;
  }
#endif
  __syncthreads();
  if (threadIdx.x < G_N) {
    int g = threadIdx.x;
    sga[g] = (sg[g * 4 + 2] - sg[g * 4 + 0]) * (sg[g * 4 + 3] - sg[g * 4 + 1]);
  }
  __syncthreads();
  if (i >= R_N) return;

  const float4 rb = *(const float4*)(roi + ((size_t)b * R_N + i) * 4);
  float x1 = rb.x, y1 = rb.y, x2 = rb.z, y2 = rb.w;
  float ar = (x2 - x1) * (y2 - y1);

  float best = -1.0f; int bi = 0;
  for (int g = 0; g < G_N; ++g) {
    const float4 gv = ((const float4*)sg)[g];   // one ds_read_b128, broadcast
    float ix1 = fmaxf(x1, gv.x), iy1 = fmaxf(y1, gv.y);
    float ix2 = fminf(x2, gv.z), iy2 = fminf(y2, gv.w);
    float iw = fmaxf(ix2 - ix1, 0.0f);
    float ih = fmaxf(iy2 - iy1, 0.0f);
    float inter = iw * ih;
    float denom = (ar + sga[g]) - inter;
    float iou = inter / denom;                  // IEEE divide, same as XLA
    if (iou > best) { best = iou; bi = g; }     // first-max like jnp.argmax
  }

  uint32_t bits;
#if JAX_PARTITIONABLE
  uint32_t t0, t1;
  tf2x32(skb[0], skb[1], 0u, (uint32_t)i, t0, t1);
  bits = t0 ^ t1;                                // 32-bit partitionable bits
#else
  uint32_t kb0, kb1, d0, d1;
  if (b < 16) {
    tf2x32(0u, 42u, (uint32_t)(2 * b),     (uint32_t)(2 * b + 32), kb0, d0);
    tf2x32(0u, 42u, (uint32_t)(2 * b + 1), (uint32_t)(2 * b + 33), kb1, d1);
  } else {
    int c = b - 16;
    tf2x32(0u, 42u, (uint32_t)(2 * c),     (uint32_t)(2 * c + 32), d0, kb0);
    tf2x32(0u, 42u, (uint32_t)(2 * c + 1), (uint32_t)(2 * c + 33), d1, kb1);
  }
  uint32_t t0, t1;
  if (i < R_N / 2) { tf2x32(kb0, kb1, (uint32_t)i, (uint32_t)(i + R_N / 2), t0, t1); bits = t0; }
  else             { tf2x32(kb0, kb1, (uint32_t)(i - R_N / 2), (uint32_t)i, t0, t1); bits = t1; }
#endif

  float r = tf_uniform(bits);
  size_t o = (size_t)b * R_N + i;
  wr[o] = (best >= 0.5f) ? -r : r;   // exact sign flip; r > 0 always
  wgta[o] = bi;
}

// Kernel 2: per-image selection + ordering + output. 1 block / image.
// Items registerized (thread t<750 owns 8t..8t+7); 9 barriers total.
__global__ __launch_bounds__(SEL_T) void select_kernel(
    const float* __restrict__ roi, const float* __restrict__ gt,
    const int* __restrict__ labels,
    const float* __restrict__ wr, const int* __restrict__ wgta,
    float* __restrict__ out) {
#pragma clang fp contract(off)
  const int b = blockIdx.x;
  const int tid = threadIdx.x;
  const int lane = tid & 63;
  const int wid = tid >> 6;
  const size_t base = (size_t)b * R_N;

  __shared__ int S[2][NBUCK];                  // histograms -> suffix sums (8KB)
  __shared__ __align__(16) float sgt[G_N * 4]; // gt boxes for epilogue
  __shared__ int slab[G_N];                    // labels for epilogue
  __shared__ int wsum[2][16];                  // wave totals for the scan
  __shared__ int bndB[2], bndA[2];             // boundary bucket / above-count per class
  __shared__ int candN[2], listN[2];
  __shared__ int   candI[2][BCAP];
  __shared__ float candV[2][BCAP];
  __shared__ int   posIdx[PMAX]; __shared__ float posR[PMAX];
  __shared__ int   negIdx[NS];   __shared__ float negR[NS];
  __shared__ int outIdxA[NS];

  // ---- init (also preload gt/labels for the epilogue) ----
  for (int t = tid; t < G_N * 4; t += SEL_T) sgt[t] = gt[(size_t)b * G_N * 4 + t];
  for (int t = tid; t < G_N; t += SEL_T) slab[t] = labels[b * G_N + t];
  for (int t = tid; t < 2 * NBUCK; t += SEL_T) ((int*)S)[t] = 0;
  if (tid < 2) { candN[tid] = 0; listN[tid] = 0; }
  __syncthreads();                                                   // B1

  // ---- pass 1: load signed r (float4 x2), classify, histogram both classes ----
  float rv[NITEM]; int bk[NITEM]; int cl[NITEM];
  if (tid < T_LOAD) {
    const float4 a0 = *(const float4*)(wr + base + (size_t)tid * NITEM);
    const float4 a1 = *(const float4*)(wr + base + (size_t)tid * NITEM + 4);
    float s[NITEM] = { a0.x, a0.y, a0.z, a0.w, a1.x, a1.y, a1.z, a1.w };
#pragma unroll
    for (int k = 0; k < NITEM; ++k) {
      float sv = s[k];
      int c = (sv < 0.0f) ? 1 : 0;
      float r = fabsf(sv);
      rv[k] = r; cl[k] = c;
      bk[k] = min((int)(r * (float)NBUCK), NBUCK - 1);   // same expr as before
      atomicAdd(&S[c][bk[k]], 1);
    }
  }
  __syncthreads();                                                   // B2

  // ---- suffix scan of both histograms: reverse-index prefix scan via shuffles ----
  {
    const int h = NBUCK - 1 - tid;          // thread t handles bucket h (reversed)
    int vp = S[1][h], vn = S[0][h];
#pragma unroll
    for (int d = 1; d < 64; d <<= 1) {
      int up = __shfl_up(vp, d);
      int un = __shfl_up(vn, d);
      if (lane >= d) { vp += up; vn += un; }
    }
    if (lane == 63) { wsum[1][wid] = vp; wsum[0][wid] = vn; }
    __syncthreads();                                                 // B3
    int op = 0, on = 0;
    for (int w = 0; w < wid; ++w) { op += wsum[1][w]; on += wsum[0][w]; }
    S[1][h] = vp + op;                      // S[c][h] = sum_{j>=h} count[c][j]
    S[0][h] = vn + on;
  }
  __syncthreads();                                                   // B4

  const int cntPos = S[1][0];
  const int nPosSel = (cntPos < PMAX) ? cntPos : PMAX;
  const int qNeg = NS - nPosSel;
  const int cntNeg = R_N - cntPos;

  // ---- boundary detection: S[Bb] >= quota, S[Bb+1] < quota (unique, monotone) ----
  if (tid == 0) {
    if (cntPos <= PMAX) { bndB[1] = -1; bndA[1] = 0; }
    if (cntNeg <= qNeg) { bndB[0] = -1; bndA[0] = 0; }
  }
  if (cntPos > PMAX) {
    int Sh = S[1][tid];
    int Sn = (tid + 1 < NBUCK) ? S[1][tid + 1] : 0;
    if (Sh >= PMAX && Sn < PMAX) { bndB[1] = tid; bndA[1] = Sn; }
  }
  if (cntNeg > qNeg) {
    int Sh = S[0][tid];
    int Sn = (tid + 1 < NBUCK) ? S[0][tid + 1] : 0;
    if (Sh >= qNeg && Sn < qNeg) { bndB[0] = tid; bndA[0] = Sn; }
  }
  __syncthreads();                                                   // B5

  // ---- pass 2: mark definite winners & boundary candidates, from registers ----
  if (tid < T_LOAD) {
#pragma unroll
    for (int k = 0; k < NITEM; ++k) {
      const int i = tid * NITEM + k;
      const int c = cl[k];
      const int Bb = bndB[c];
      if (bk[k] > Bb) {
        if (c) { int p = atomicAdd(&listN[1], 1); if (p < PMAX) { posIdx[p] = i; posR[p] = rv[k]; } }
        else   { int p = atomicAdd(&listN[0], 1); if (p < NS)   { negIdx[p] = i; negR[p] = rv[k]; } }
      } else if (bk[k] == Bb) {
        int p = atomicAdd(&candN[c], 1);
        if (p < BCAP) { candI[c][p] = i; candV[c][p] = rv[k]; }
      }
    }
  }
  __syncthreads();                                                   // B6

  // ---- resolve boundary candidates (both classes concurrently); M ~ 6 expected ----
  {
    const int c = (tid < 512) ? 1 : 0;
    const int m = (tid < 512) ? tid : tid - 512;
    const int M = candN[c];
    if (M <= BCAP && m < M) {
      const int i = candI[c][m]; const float ri = candV[c][m];
      const int A = bndA[c];
      const int q = c ? PMAX : qNeg;
      int beats = 0;
      for (int u = 0; u < M; ++u) {
        float rj = candV[c][u]; int j = candI[c][u];
        if (rj > ri || (rj == ri && j < i)) beats++;
      }
      if (A + beats < q) {
        if (c) { int p = atomicAdd(&listN[1], 1); if (p < PMAX) { posIdx[p] = i; posR[p] = ri; } }
        else   { int p = atomicAdd(&listN[0], 1); if (p < NS)   { negIdx[p] = i; negR[p] = ri; } }
      }
    }
  }
  // fallback (statistically never: >512 items in one of 1024 buckets)
#pragma unroll
  for (int c = 0; c < 2; ++c) {
    if (candN[c] > BCAP) {          // shared read -> block-uniform branch
      const int q = c ? PMAX : qNeg;
      const int A = bndA[c], Bb = bndB[c];
      if (tid < T_LOAD) {
#pragma unroll
        for (int k = 0; k < NITEM; ++k) {
          const int i = tid * NITEM + k;
          if (cl[k] == c && bk[k] == Bb) {
            const float ri = rv[k];
            int beats = 0;
            for (int j = 0; j < R_N; ++j) {
              float sj = wr[base + j];
              int cj = (sj < 0.0f) ? 1 : 0;
              if (cj == c) {
                float rj = fabsf(sj);
                int bj = min((int)(rj * (float)NBUCK), NBUCK - 1);
                if (bj == Bb && (rj > ri || (rj == ri && j < i))) beats++;
              }
            }
            if (A + beats < q) {
              if (c) { int p = atomicAdd(&listN[1], 1); if (p < PMAX) { posIdx[p] = i; posR[p] = ri; } }
              else   { int p = atomicAdd(&listN[0], 1); if (p < NS)   { negIdx[p] = i; negR[p] = ri; } }
            }
          }
        }
      }
    }
  }
  __syncthreads();                                                   // B7

  const int nP = min(listN[1], PMAX);
  const int nN = min(listN[0], NS);

  if (tid < NS) outIdxA[tid] = -1;
  __syncthreads();                                                   // B8

  // ---- output slots: top_k on prio (2+r pos, 1+r neg), ties -> lower index.
  // Note: prio is the float32-rounded SUM (distinct r can tie) — kept exactly.
  if (tid < nP) {
    const int i = posIdx[tid]; const float pr = 2.0f + posR[tid];
    int slot = 0;
    for (int u = 0; u < nP; ++u) {
      float pj = 2.0f + posR[u]; int j = posIdx[u];
      if (pj > pr || (pj == pr && j < i)) slot++;
    }
    outIdxA[slot] = i;
  }
  if (tid >= 128 && (tid - 128) < nN) {
    const int m = tid - 128;
    const int i = negIdx[m]; const float pr = 1.0f + negR[m];
    int slot = 0;
    for (int u = 0; u < nN; ++u) {
      float pj = 1.0f + negR[u]; int j = negIdx[u];
      if (pj > pr || (pj == pr && j < i)) slot++;
    }
    outIdxA[nP + slot] = i;
  }
  __syncthreads();                                                   // B9

  // ---- epilogue: write all three outputs (zeros for invalid filler slots) ----
  if (tid < NS) {
    const int p = tid;
    const int i = outIdxA[p];
    float4 o_roi = { 0.f, 0.f, 0.f, 0.f };
    float o_lab = 0.f;
    float4 o_d = { 0.f, 0.f, 0.f, 0.f };
    if (i >= 0) {
      const float4 rr = *(const float4*)(roi + (base + (size_t)i) * 4);
      float x1 = rr.x, y1 = rr.y, x2 = rr.z, y2 = rr.w;
      o_roi = rr;
      const int g = wgta[base + (size_t)i];
      float gx1 = sgt[g * 4 + 0], gy1 = sgt[g * 4 + 1];
      float gx2 = sgt[g * 4 + 2], gy2 = sgt[g * 4 + 3];
      if (p < nP) o_lab = (float)slab[g];   // slots [0,nP) are exactly the positives
      const float EPSF = 1.1920928955078125e-7f;  // np.finfo(f32).eps
      float w = fmaxf(x2 - x1, EPSF);
      float h = fmaxf(y2 - y1, EPSF);
      float cx = x1 + 0.5f * (x2 - x1);
      float cy = y1 + 0.5f * (y2 - y1);
      float bw = gx2 - gx1, bh = gy2 - gy1;
      float bcx = gx1 + 0.5f * bw, bcy = gy1 + 0.5f * bh;
      o_d.x = (bcx - cx) / w;
      o_d.y = (bcy - cy) / h;
      o_d.z = logf(bw / w);
      o_d.w = logf(bh / h);
    }
    float* out0 = out;                                 // [32,128,4]
    float* out1 = out + (size_t)B_IMG * NS * 4;        // [32,128]
    float* out2 = out1 + (size_t)B_IMG * NS;           // [32,128,4]
    const int basei = b * NS + p;
    *(float4*)(out0 + (size_t)basei * 4) = o_roi;
    out1[basei] = o_lab;
    *(float4*)(out2 + (size_t)basei * 4) = o_d;
  }
}

extern "C" void kernel_launch(void* const* d_in, const int* in_sizes, int n_in,
                              void* d_out, int out_size, void* d_ws, size_t ws_size,
                              hipStream_t stream) {
  const float* roi    = (const float*)d_in[0];
  const float* gt     = (const float*)d_in[1];
  const int*   labels = (const int*)d_in[2];
  // d_in[3] (image) is unused by the math.

  float* wr   = (float*)d_ws;                       // [32*6000] signed r (sign = pos class)
  int*   wgta = (int*)(wr + (size_t)B_IMG * R_N);   // [32*6000] argmax gt

  dim3 g1((R_N + 255) / 256, B_IMG);
  prep_kernel<<<g1, 256, 0, stream>>>(roi, gt, wr, wgta);
  select_kernel<<<B_IMG, SEL_T, 0, stream>>>(roi, gt, labels, wr, wgta,
                                             (float*)d_out);
}